// Round 4
// baseline (281.739 us; speedup 1.0000x reference)
//
#include <hip/hip_runtime.h>
#include <hip/hip_bf16.h>

typedef __attribute__((ext_vector_type(8))) short short8;
typedef __attribute__((ext_vector_type(4))) float f32x4;

// ws layout (bytes)
#define WFT_OFF 0          // bf16[256*512]          = 262144 B
#define HB_OFF  262144     // f32[32*256]            =  32768 B
#define SC_OFF  294912     // f32[131072] scores     = 524288 B
#define ST_OFF  819200     // f32[4096*2] m,l        =  32768 B
#define CP_OFF  851968     // f32[4096*512] ctx part = 8388608 B (total ~9.2 MB)

// LDS per block (64.6 KB -> 2 blocks/CU):
//   Ab dbuf 2x [32][1024 B] bf16 swizzled @0 / @32768
//   wpart [4][32] f32 @65536 (512 B)
//   wbuf  [32]    f32 @66048 (128 B)
#define SMEM_MAIN 66176

__device__ __forceinline__ float bf2f(unsigned short h) {
    unsigned u = ((unsigned)h) << 16;
    return __builtin_bit_cast(float, u);
}
__device__ __forceinline__ unsigned pack_bf16(float a, float b) {
    unsigned short sa = __builtin_bit_cast(unsigned short, __float2bfloat16(a));
    unsigned short sb = __builtin_bit_cast(unsigned short, __float2bfloat16(b));
    return (unsigned)sa | ((unsigned)sb << 16);
}
__device__ __forceinline__ float fast_tanh(float x) {
    float e2 = __expf(2.0f * x);
    return 1.0f - 2.0f / (e2 + 1.0f);
}
// LDS-only barrier: no vmcnt drain — keeps the A/B global-load stream in flight.
__device__ __forceinline__ void lds_barrier() {
    asm volatile("s_waitcnt lgkmcnt(0)" ::: "memory");
    __builtin_amdgcn_s_barrier();
}

// ---- Wf (512x256 f32) -> WfT (256x512 bf16), tiled transpose ----
__global__ void wft_kernel(const float* __restrict__ Wf, unsigned short* __restrict__ WfT) {
    __shared__ unsigned short tl[64 * 80];
    const int t = threadIdx.x;
    const int tk = blockIdx.x >> 2, ta = blockIdx.x & 3;
    const int d0 = tk * 64, a0 = ta * 64;
#pragma unroll
    for (int i = 0; i < 16; ++i) {
        int flat = t + 256 * i;
        int dl = flat >> 6, al = flat & 63;
        tl[al * 80 + dl] = __builtin_bit_cast(unsigned short,
                               __float2bfloat16(Wf[(d0 + dl) * 256 + a0 + al]));
    }
    __syncthreads();
#pragma unroll
    for (int i = 0; i < 2; ++i) {
        int u = t + 256 * i;
        int al = u >> 3, q = u & 7;
        *(uint4*)(&WfT[(size_t)(a0 + al) * 512 + d0 + q * 8]) =
            *(const uint4*)(&tl[al * 80 + q * 8]);
    }
}

// ---- hb[b][a] = hidden[b]·Wh[:,a] + bh[a] + bf[a] ----
__global__ void hb_kernel(const float* __restrict__ hidden, const float* __restrict__ Wh,
                          const float* __restrict__ bh, const float* __restrict__ bfv,
                          float* __restrict__ hb) {
    const int b = blockIdx.x, a = threadIdx.x;
    float acc = bh[a] + bfv[a];
    const float* hrow = hidden + b * 512;
#pragma unroll 8
    for (int d = 0; d < 512; ++d)
        acc += hrow[d] * Wh[d * 256 + a];
    hb[b * 256 + a] = acc;
}

// ---- persistent fused kernel: 512 blocks (2/CU) x 8 tiles of 32 rows ----
// Per tile: ds_write A from reg-burst -> barrier -> GEMM with 1 A-load/ks
// interleaved (vmcnt-counted, never drained) + 1-deep B prefetch from L2
// -> tanh epilogue -> stats -> ctx partial. A is double-buffered in LDS.
__launch_bounds__(256, 2)
__global__ void main_kernel(const float* __restrict__ feats,
                            const unsigned short* __restrict__ WfT,
                            const float* __restrict__ hbg,
                            const float* __restrict__ Ws,
                            float* __restrict__ scores,
                            float* __restrict__ stats,
                            float* __restrict__ ctxp) {
    extern __shared__ char smem[];
    float* wpart = (float*)(smem + 65536);      // [4][32]
    float* wbuf  = (float*)(smem + 66048);      // [32]

    const int t = threadIdx.x;
    const int bid = blockIdx.x;
    const int lane = t & 63, w = t >> 6;        // 4 waves; wave w owns cols w*64..+63
    const int lr = lane & 15, lg = lane >> 4;
    const int sw = (lr & 7) << 4;
    const int col4 = t & 127, r0 = t >> 7;

    const float4* feats4 = (const float4*)feats;

    // prologue burst: tile 0's A (16 KB/wave in flight)
    float4 areg[16];
    {
        const float4* f0 = feats4 + (size_t)bid * 4096;
#pragma unroll
        for (int ks = 0; ks < 16; ++ks)
            areg[ks] = f0[t + ks * 256];
    }

    for (int it = 0; it < 8; ++it) {
        const int tile = bid + it * 512;
        const int b = tile >> 7;
        const int row0 = tile * 32;
        char* Ab = smem + ((it & 1) << 15);     // A double buffer

        // epilogue operands: oldest loads of the tile, retire with the A batch
        float hbv[4], wsv[4];
#pragma unroll
        for (int j = 0; j < 4; ++j) {
            int col = w * 64 + j * 16 + lr;
            hbv[j] = hbg[b * 256 + col];
            wsv[j] = Ws[col];
        }

        // stage A tile from reg burst (compiler inserts progressive vmcnt waits)
#pragma unroll
        for (int ks = 0; ks < 16; ++ks) {
            int row = r0 + 2 * ks;
            float4 v = areg[ks];
            uint2 u;
            u.x = pack_bf16(v.x, v.y);
            u.y = pack_bf16(v.z, v.w);
            *(uint2*)(Ab + row * 1024 + ((col4 * 8) ^ ((row & 7) << 4))) = u;
        }

        lds_barrier();                          // A tile visible to all 4 waves

        // ---- GEMM 32x256x512; next tile's A streamed 1 load/ks ----
        const unsigned short* bpw = WfT + (size_t)(w * 64 + lr) * 512 + lg * 8;
        uint4 bfr[2][4];
#pragma unroll
        for (int j = 0; j < 4; ++j)
            bfr[0][j] = *(const uint4*)(bpw + (size_t)j * 8192);

        const bool hn = (it < 7);
        const float4* fnext = feats4 + (size_t)(tile + (hn ? 512 : 0)) * 4096;

        f32x4 acc[2][4] = {};
#pragma unroll
        for (int ks = 0; ks < 16; ++ks) {
            const int cur = ks & 1, nxt = cur ^ 1;
            if (hn) areg[ks] = fnext[t + ks * 256];   // stays in flight across ks
            if (ks < 15) {
#pragma unroll
                for (int j = 0; j < 4; ++j)
                    bfr[nxt][j] = *(const uint4*)(bpw + (size_t)j * 8192 + (ks + 1) * 32);
            }
            short8 af[2];
#pragma unroll
            for (int i = 0; i < 2; ++i) {
                int row = i * 16 + lr;
                af[i] = *(const short8*)(Ab + row * 1024 + ((ks * 64 + lg * 16) ^ sw));
            }
#pragma unroll
            for (int i = 0; i < 2; ++i)
#pragma unroll
                for (int j = 0; j < 4; ++j)
                    acc[i][j] = __builtin_amdgcn_mfma_f32_16x16x32_bf16(
                        af[i], __builtin_bit_cast(short8, bfr[cur][j]), acc[i][j], 0, 0, 0);
        }

        // ---- epilogue: scores = sum_a tanh(C + hb[a]) * Ws[a] ----
#pragma unroll
        for (int i = 0; i < 2; ++i) {
#pragma unroll
            for (int r = 0; r < 4; ++r) {
                float p = 0.f;
#pragma unroll
                for (int j = 0; j < 4; ++j)
                    p += fast_tanh(acc[i][j][r] + hbv[j]) * wsv[j];
#pragma unroll
                for (int off = 1; off < 16; off <<= 1) p += __shfl_xor(p, off, 64);
                if (lr == 0) wpart[w * 32 + i * 16 + lg * 4 + r] = p;
            }
        }
        lds_barrier();

        // block softmax stats (first 32 lanes)
        if (t < 32) {
            float s = wpart[t] + wpart[32 + t] + wpart[64 + t] + wpart[96 + t];
            scores[row0 + t] = s;
            float m = s;
#pragma unroll
            for (int off = 1; off < 32; off <<= 1) m = fmaxf(m, __shfl_xor(m, off, 32));
            float e = __expf(s - m);
            float l = e;
#pragma unroll
            for (int off = 1; off < 32; off <<= 1) l += __shfl_xor(l, off, 32);
            wbuf[t] = e;
            if (t == 0) { stats[tile * 2] = m; stats[tile * 2 + 1] = l; }
        }
        lds_barrier();

        // ---- ctx partial: thread t owns d-cols {2t, 2t+1} ----
        {
            float c0 = 0.f, c1 = 0.f;
            const int byt = t * 4;
#pragma unroll 8
            for (int n = 0; n < 32; ++n) {
                float wv = wbuf[n];
                unsigned a2 = *(const unsigned*)(Ab + n * 1024 + (byt ^ ((n & 7) << 4)));
                c0 += wv * bf2f((unsigned short)a2);
                c1 += wv * bf2f((unsigned short)(a2 >> 16));
            }
            float2 v; v.x = c0; v.y = c1;
            *(float2*)(ctxp + (size_t)tile * 512 + t * 2) = v;
        }
        // next iteration's staging writes go to the OTHER A buffer; the
        // pre-GEMM barrier there also fences wpart/wbuf reuse.
    }
}

// ---- per-batch: global softmax (128 partials) + alpha + ctx merge ----
__global__ void combine_kernel(const float* __restrict__ scores,
                               const float* __restrict__ stats,
                               const float* __restrict__ ctxp,
                               float* __restrict__ out_ctx,
                               float* __restrict__ out_alpha) {
    __shared__ float scales[128];
    __shared__ float red[4];
    const int b = blockIdx.x, t = threadIdx.x;
    float mk = -1e30f, lk = 0.f, e = 0.f;
    if (t < 128) {
        mk = stats[(b * 128 + t) * 2];
        lk = stats[(b * 128 + t) * 2 + 1];
    }
    float M = mk;
#pragma unroll
    for (int off = 1; off < 64; off <<= 1) M = fmaxf(M, __shfl_xor(M, off, 64));
    if ((t & 63) == 0) red[t >> 6] = M;
    __syncthreads();
    M = fmaxf(red[0], red[1]);
    if (t < 128) e = __expf(mk - M);
    float z = e * lk;
#pragma unroll
    for (int off = 1; off < 64; off <<= 1) z += __shfl_xor(z, off, 64);
    __syncthreads();                            // red[] reuse
    if ((t & 63) == 0) red[t >> 6] = z;
    __syncthreads();
    const float Z = red[0] + red[1];
    if (t < 128) scales[t] = e / Z;
    __syncthreads();

    const float invZ = 1.0f / Z;
    const float* sb = scores + b * 4096;
    float* abp = out_alpha + b * 4096;
#pragma unroll
    for (int i = 0; i < 16; ++i) {
        int n = t + 256 * i;
        abp[n] = __expf(sb[n] - M) * invZ;
    }
    // ctx merge: 8-wide unroll keeps 8 independent loads in flight
    const int d0 = t * 2;
    const float* cb = ctxp + (size_t)b * 128 * 512;
    float accx = 0.f, accy = 0.f;
    for (int k0 = 0; k0 < 128; k0 += 8) {
        float2 v[8]; float s[8];
#pragma unroll
        for (int u = 0; u < 8; ++u) {
            s[u] = scales[k0 + u];
            v[u] = *(const float2*)(cb + (size_t)(k0 + u) * 512 + d0);
        }
#pragma unroll
        for (int u = 0; u < 8; ++u) { accx += s[u] * v[u].x; accy += s[u] * v[u].y; }
    }
    float2 o; o.x = accx; o.y = accy;
    *(float2*)(out_ctx + b * 512 + d0) = o;
}

extern "C" void kernel_launch(void* const* d_in, const int* in_sizes, int n_in,
                              void* d_out, int out_size, void* d_ws, size_t ws_size,
                              hipStream_t stream) {
    (void)in_sizes; (void)n_in; (void)out_size; (void)ws_size;
    const float* feats  = (const float*)d_in[0];
    const float* hidden = (const float*)d_in[1];
    const float* Wf     = (const float*)d_in[2];
    const float* bfv    = (const float*)d_in[3];
    const float* Wh     = (const float*)d_in[4];
    const float* bh     = (const float*)d_in[5];
    const float* Ws     = (const float*)d_in[6];
    // d_in[7] (bs) irrelevant: softmax is shift-invariant and scores are not output.

    char* ws = (char*)d_ws;
    unsigned short* WfT = (unsigned short*)(ws + WFT_OFF);
    float* hb     = (float*)(ws + HB_OFF);
    float* scores = (float*)(ws + SC_OFF);
    float* stats  = (float*)(ws + ST_OFF);
    float* ctxp   = (float*)(ws + CP_OFF);

    float* out_ctx   = (float*)d_out;
    float* out_alpha = out_ctx + 32 * 512;

    hipFuncSetAttribute((const void*)main_kernel,
                        hipFuncAttributeMaxDynamicSharedMemorySize, SMEM_MAIN);

    hipLaunchKernelGGL(wft_kernel, dim3(32), dim3(256), 0, stream, Wf, WfT);
    hipLaunchKernelGGL(hb_kernel, dim3(32), dim3(256), 0, stream, hidden, Wh, bh, bfv, hb);
    hipLaunchKernelGGL(main_kernel, dim3(512), dim3(256), SMEM_MAIN, stream,
                       feats, WfT, hb, Ws, scores, stats, ctxp);
    hipLaunchKernelGGL(combine_kernel, dim3(32), dim3(256), 0, stream,
                       scores, stats, ctxp, out_ctx, out_alpha);
}

// Round 5
// 227.525 us; speedup vs baseline: 1.2383x; 1.2383x over previous
//
#include <hip/hip_runtime.h>
#include <hip/hip_bf16.h>

typedef __attribute__((ext_vector_type(8))) short short8;
typedef __attribute__((ext_vector_type(4))) float f32x4;

// ws layout (bytes)
#define WFT_OFF 0          // bf16[256*512]          = 262144 B
#define HB_OFF  262144     // f32[32*256]            =  32768 B
#define SC_OFF  294912     // f32[131072] scores     = 524288 B
#define ST_OFF  819200     // f32[2048*2] m,l        =  16384 B
#define CP_OFF  835584     // f32[2048*512] ctx part = 4194304 B (ends 5029888)
#define IMG_OFF 8388608    // bf16 feats image, swizzled tile layout
#define IMG_SZ  134217728  // 2048 tiles x 64 KB
#define WS_NEED (IMG_OFF + IMG_SZ)

// main_img LDS: Ab dbuf 2x[64][1024B] @0/@65536, wpart[8][64] @131072,
//               wbuf[64] @133120, scratch[8][512] @133376  -> 149760 B
#define SMEM_IMG 149760
// fallback (R2) LDS
#define SMEM_FB  76032

__device__ __forceinline__ float bf2f(unsigned short h) {
    unsigned u = ((unsigned)h) << 16;
    return __builtin_bit_cast(float, u);
}
__device__ __forceinline__ unsigned pack_bf16(float a, float b) {
    unsigned short sa = __builtin_bit_cast(unsigned short, __float2bfloat16(a));
    unsigned short sb = __builtin_bit_cast(unsigned short, __float2bfloat16(b));
    return (unsigned)sa | ((unsigned)sb << 16);
}
__device__ __forceinline__ float fast_tanh(float x) {
    float e2 = __expf(2.0f * x);
    return 1.0f - 2.0f / (e2 + 1.0f);
}
__device__ __forceinline__ void lds_barrier() {
    asm volatile("s_waitcnt lgkmcnt(0)" ::: "memory");
    __builtin_amdgcn_s_barrier();
}
// async global->LDS, 16 B per lane; LDS dest is wave-uniform base + lane*16
__device__ __forceinline__ void gld_lds16(const char* g, char* l) {
    __builtin_amdgcn_global_load_lds(
        (const __attribute__((address_space(1))) void*)g,
        (__attribute__((address_space(3))) void*)l, 16, 0, 0);
}

// ---- Wf (512x256 f32) -> WfT (256x512 bf16), tiled transpose ----
__global__ void wft_kernel(const float* __restrict__ Wf, unsigned short* __restrict__ WfT) {
    __shared__ unsigned short tl[64 * 80];
    const int t = threadIdx.x;
    const int tk = blockIdx.x >> 2, ta = blockIdx.x & 3;
    const int d0 = tk * 64, a0 = ta * 64;
#pragma unroll
    for (int i = 0; i < 16; ++i) {
        int flat = t + 256 * i;
        int dl = flat >> 6, al = flat & 63;
        tl[al * 80 + dl] = __builtin_bit_cast(unsigned short,
                               __float2bfloat16(Wf[(d0 + dl) * 256 + a0 + al]));
    }
    __syncthreads();
#pragma unroll
    for (int i = 0; i < 2; ++i) {
        int u = t + 256 * i;
        int al = u >> 3, q = u & 7;
        *(uint4*)(&WfT[(size_t)(a0 + al) * 512 + d0 + q * 8]) =
            *(const uint4*)(&tl[al * 80 + q * 8]);
    }
}

// ---- hb[b][a] = hidden[b]·Wh[:,a] + bh[a] + bf[a] ----
__global__ void hb_kernel(const float* __restrict__ hidden, const float* __restrict__ Wh,
                          const float* __restrict__ bh, const float* __restrict__ bfv,
                          float* __restrict__ hb) {
    const int b = blockIdx.x, a = threadIdx.x;
    float acc = bh[a] + bfv[a];
    const float* hrow = hidden + b * 512;
#pragma unroll 8
    for (int d = 0; d < 512; ++d)
        acc += hrow[d] * Wh[d * 256 + a];
    hb[b * 256 + a] = acc;
}

// ---- prep: feats f32 -> bf16 tile image in the exact swizzled LDS byte layout ----
// tile = 64 rows; image[tile][row*1024 + ((q*16)^((row&7)<<4))] = bf16 cols 8q..8q+7.
// Pure stream: 268 MB read, 134 MB write. Writes XOR-permute 16B blocks within
// 128B lines -> fully coalesced.
__global__ void prep_kernel(const float* __restrict__ feats, char* __restrict__ img) {
    const int t = threadIdx.x;
    const size_t tile = blockIdx.x;
    const char* src = (const char*)feats + tile * 131072;
    char* dst = img + tile * 65536;
#pragma unroll
    for (int i = 0; i < 16; ++i) {
        int flat = t + 256 * i;
        int r = flat >> 6, q = flat & 63;
        const float4* s = (const float4*)(src + r * 2048 + q * 32);
        float4 v0 = s[0], v1 = s[1];
        uint4 u;
        u.x = pack_bf16(v0.x, v0.y); u.y = pack_bf16(v0.z, v0.w);
        u.z = pack_bf16(v1.x, v1.y); u.w = pack_bf16(v1.z, v1.w);
        *(uint4*)(dst + r * 1024 + ((q * 16) ^ ((r & 7) << 4))) = u;
    }
}

// ---- main (image path): persistent 256 blocks x 8 tiles of 64 rows ----
// A staged by async global_load_lds (zero VGPR/VALU), double-buffered; next
// tile's loads fly under current tile's GEMM/epilogue; one counted vmcnt(8)
// per tile, never draining mid-pipeline. B streamed from L2 with depth-2
// register prefetch.
__launch_bounds__(512, 2)
__global__ void main_img(const char* __restrict__ img,
                         const unsigned short* __restrict__ WfT,
                         const float* __restrict__ hbg,
                         const float* __restrict__ Ws,
                         float* __restrict__ scores,
                         float* __restrict__ stats,
                         float* __restrict__ ctxp) {
    extern __shared__ char smem[];
    float* wpart   = (float*)(smem + 131072);   // [8][64]
    float* wbuf    = (float*)(smem + 133120);   // [64]
    float* scratch = (float*)(smem + 133376);   // [8][512]

    const int t = threadIdx.x, bid = blockIdx.x;
    const int lane = t & 63, w = t >> 6;        // 8 waves; wave w owns cols w*32..+31
    const int lr = lane & 15, lg = lane >> 4;
    const int sw = (lr & 7) << 4;
    const int b = bid >> 3;                     // 8 consecutive tiles per block -> b const

    // hoisted epilogue operands (oldest VMEM; drained by first vmcnt(8))
    float hbv[2], wsv[2];
#pragma unroll
    for (int j = 0; j < 2; ++j) {
        int col = w * 32 + j * 16 + lr;
        hbv[j] = hbg[b * 256 + col];
        wsv[j] = Ws[col];
    }

    // prologue: tile0 -> buf0 (8 x 1KB per wave, async)
    {
        const char* src = img + (size_t)(bid * 8) * 65536 + w * 8192 + lane * 16;
        char* dst = smem + w * 8192;
#pragma unroll
        for (int i = 0; i < 8; ++i) gld_lds16(src + i * 1024, dst + i * 1024);
    }

    for (int it = 0; it < 8; ++it) {
        const int tile = bid * 8 + it;
        const int row0 = tile * 64;
        char* Ab = smem + ((it & 1) << 16);

        // issue next tile's A into the other buffer, then counted wait:
        // vmcnt(8) = only my 8 fresh loads may remain in flight.
        if (it < 7) {
            const char* src = img + (size_t)(tile + 1) * 65536 + w * 8192 + lane * 16;
            char* dst = smem + (((it + 1) & 1) << 16) + w * 8192;
#pragma unroll
            for (int i = 0; i < 8; ++i) gld_lds16(src + i * 1024, dst + i * 1024);
            asm volatile("s_waitcnt vmcnt(8)" ::: "memory");
        } else {
            asm volatile("s_waitcnt vmcnt(0)" ::: "memory");
        }
        __builtin_amdgcn_s_barrier();           // all waves' tile-it data present

        // ---- GEMM 64x256x512: wave w -> 64 rows x 32 cols, K chunks of 32 ----
        const unsigned short* bp0 = WfT + (size_t)(w * 32 + lr) * 512 + lg * 8;
        const unsigned short* bp1 = WfT + (size_t)(w * 32 + 16 + lr) * 512 + lg * 8;
        uint4 bq[2][2];                         // depth-2 B prefetch (L2 latency cover)
        bq[0][0] = *(const uint4*)(bp0);
        bq[0][1] = *(const uint4*)(bp1);
        bq[1][0] = *(const uint4*)(bp0 + 32);
        bq[1][1] = *(const uint4*)(bp1 + 32);

        f32x4 acc[4][2] = {};
#pragma unroll
        for (int ks = 0; ks < 16; ++ks) {
            const int p = ks & 1;
            short8 af[4];
#pragma unroll
            for (int i = 0; i < 4; ++i) {
                int row = i * 16 + lr;
                af[i] = *(const short8*)(Ab + row * 1024 + ((ks * 64 + lg * 16) ^ sw));
            }
            short8 b0 = __builtin_bit_cast(short8, bq[p][0]);
            short8 b1 = __builtin_bit_cast(short8, bq[p][1]);
            if (ks < 14) {
                bq[p][0] = *(const uint4*)(bp0 + (ks + 2) * 32);
                bq[p][1] = *(const uint4*)(bp1 + (ks + 2) * 32);
            }
#pragma unroll
            for (int i = 0; i < 4; ++i) {
                acc[i][0] = __builtin_amdgcn_mfma_f32_16x16x32_bf16(af[i], b0, acc[i][0], 0, 0, 0);
                acc[i][1] = __builtin_amdgcn_mfma_f32_16x16x32_bf16(af[i], b1, acc[i][1], 0, 0, 0);
            }
        }

        // ---- epilogue: scores = sum_a tanh(C + hb[a]) * Ws[a] ----
#pragma unroll
        for (int i = 0; i < 4; ++i) {
#pragma unroll
            for (int r = 0; r < 4; ++r) {
                float p = fast_tanh(acc[i][0][r] + hbv[0]) * wsv[0]
                        + fast_tanh(acc[i][1][r] + hbv[1]) * wsv[1];
#pragma unroll
                for (int off = 1; off < 16; off <<= 1) p += __shfl_xor(p, off, 64);
                if (lr == 0) wpart[w * 64 + i * 16 + lg * 4 + r] = p;
            }
        }
        lds_barrier();

        // block softmax stats (wave 0)
        if (t < 64) {
            float s = 0.f;
#pragma unroll
            for (int k = 0; k < 8; ++k) s += wpart[k * 64 + t];
            scores[row0 + t] = s;
            float m = s;
#pragma unroll
            for (int off = 1; off < 64; off <<= 1) m = fmaxf(m, __shfl_xor(m, off, 64));
            float e = __expf(s - m);
            float l = e;
#pragma unroll
            for (int off = 1; off < 64; off <<= 1) l += __shfl_xor(l, off, 64);
            wbuf[t] = e;
            if (t == 0) { stats[tile * 2] = m; stats[tile * 2 + 1] = l; }
        }
        lds_barrier();

        // ---- ctx partial from LDS-resident bf16 A tile ----
        {
            float accd[8] = {};
            const int nset = t >> 6, dg = t & 63;
            const int d0 = dg * 8;
#pragma unroll
            for (int nn = 0; nn < 8; ++nn) {
                int n = nset * 8 + nn;
                float wv = wbuf[n];
                short8 av = *(const short8*)(Ab + n * 1024 + ((d0 * 2) ^ ((n & 7) << 4)));
#pragma unroll
                for (int e = 0; e < 8; ++e)
                    accd[e] += wv * bf2f((unsigned short)av[e]);
            }
            float4 v0, v1;
            v0.x = accd[0]; v0.y = accd[1]; v0.z = accd[2]; v0.w = accd[3];
            v1.x = accd[4]; v1.y = accd[5]; v1.z = accd[6]; v1.w = accd[7];
            *(float4*)(scratch + nset * 512 + d0) = v0;
            *(float4*)(scratch + nset * 512 + d0 + 4) = v1;
        }
        lds_barrier();
        {
            float s = 0.f;
#pragma unroll
            for (int ns = 0; ns < 8; ++ns) s += scratch[ns * 512 + t];
            ctxp[(size_t)tile * 512 + t] = s;
        }
        lds_barrier();   // all waves done reading Ab before next gld_lds overwrites buf^1
    }
}

// ---- fallback main (R2 verbatim, proven 164 us): used when ws too small ----
__launch_bounds__(512, 4)
__global__ void main_fb(const float* __restrict__ feats,
                        const unsigned short* __restrict__ WfT,
                        const float* __restrict__ hbg,
                        const float* __restrict__ Ws,
                        float* __restrict__ scores,
                        float* __restrict__ stats,
                        float* __restrict__ ctxp) {
    extern __shared__ char smem[];
    char* Ab       = smem;
    float* scratch = (float*)(smem + 65536);
    float* wpart   = (float*)(smem + 73728);
    float* wbuf    = (float*)(smem + 75776);

    const int t = threadIdx.x;
    const int tile = blockIdx.x;
    const int b = tile >> 6;
    const int row0 = tile * 64;
    const int lane = t & 63, w = t >> 6;
    const int lr = lane & 15, lg = lane >> 4;
    const int sw = (lr & 7) << 4;

    {
        const int ar = t >> 3;
        const int c8 = t & 7;
        const float4* fr = (const float4*)(feats + (size_t)(row0 + ar) * 512);
        char* arow = Ab + ar * 1024;
        const int rsw = (ar & 7) << 4;
#pragma unroll
        for (int i = 0; i < 16; ++i) {
            int f4 = c8 + i * 8;
            float4 v = fr[f4];
            uint2 u;
            u.x = pack_bf16(v.x, v.y);
            u.y = pack_bf16(v.z, v.w);
            *(uint2*)(arow + ((f4 * 8) ^ rsw)) = u;
        }
    }

    float hbv[2], wsv[2];
#pragma unroll
    for (int j = 0; j < 2; ++j) {
        int col = w * 32 + j * 16 + lr;
        hbv[j] = hbg[b * 256 + col];
        wsv[j] = Ws[col];
    }

    lds_barrier();

    f32x4 acc[4][2] = {};
    const unsigned short* bp0 = WfT + (size_t)(w * 32 + lr) * 512 + lg * 8;
    const unsigned short* bp1 = WfT + (size_t)(w * 32 + 16 + lr) * 512 + lg * 8;

    uint4 bfr[2][2];
    bfr[0][0] = *(const uint4*)(bp0);
    bfr[0][1] = *(const uint4*)(bp1);
#pragma unroll
    for (int ks = 0; ks < 16; ++ks) {
        const int cur = ks & 1, nxt = cur ^ 1;
        if (ks < 15) {
            bfr[nxt][0] = *(const uint4*)(bp0 + (ks + 1) * 32);
            bfr[nxt][1] = *(const uint4*)(bp1 + (ks + 1) * 32);
        }
        short8 af[4];
#pragma unroll
        for (int i = 0; i < 4; ++i) {
            int row = i * 16 + lr;
            af[i] = *(const short8*)(Ab + row * 1024 + ((ks * 64 + lg * 16) ^ sw));
        }
        short8 b0 = __builtin_bit_cast(short8, bfr[cur][0]);
        short8 b1 = __builtin_bit_cast(short8, bfr[cur][1]);
#pragma unroll
        for (int i = 0; i < 4; ++i) {
            acc[i][0] = __builtin_amdgcn_mfma_f32_16x16x32_bf16(af[i], b0, acc[i][0], 0, 0, 0);
            acc[i][1] = __builtin_amdgcn_mfma_f32_16x16x32_bf16(af[i], b1, acc[i][1], 0, 0, 0);
        }
    }

#pragma unroll
    for (int i = 0; i < 4; ++i) {
#pragma unroll
        for (int r = 0; r < 4; ++r) {
            float p = fast_tanh(acc[i][0][r] + hbv[0]) * wsv[0]
                    + fast_tanh(acc[i][1][r] + hbv[1]) * wsv[1];
#pragma unroll
            for (int off = 1; off < 16; off <<= 1) p += __shfl_xor(p, off, 64);
            if (lr == 0) wpart[w * 64 + i * 16 + lg * 4 + r] = p;
        }
    }
    lds_barrier();

    if (t < 64) {
        float s = 0.f;
#pragma unroll
        for (int k = 0; k < 8; ++k) s += wpart[k * 64 + t];
        scores[row0 + t] = s;
        float m = s;
#pragma unroll
        for (int off = 1; off < 64; off <<= 1) m = fmaxf(m, __shfl_xor(m, off, 64));
        float e = __expf(s - m);
        float l = e;
#pragma unroll
        for (int off = 1; off < 64; off <<= 1) l += __shfl_xor(l, off, 64);
        wbuf[t] = e;
        if (t == 0) { stats[tile * 2] = m; stats[tile * 2 + 1] = l; }
    }
    lds_barrier();

    {
        const int nset = t >> 7;
        const int dt = t & 127;
        float accd[4] = {};
#pragma unroll
        for (int nn = 0; nn < 16; ++nn) {
            int n = nset * 16 + nn;
            float wv = wbuf[n];
            unsigned long long a8 =
                *(const unsigned long long*)(Ab + n * 1024 + ((dt * 8) ^ ((n & 7) << 4)));
            accd[0] += wv * bf2f((unsigned short)(a8));
            accd[1] += wv * bf2f((unsigned short)(a8 >> 16));
            accd[2] += wv * bf2f((unsigned short)(a8 >> 32));
            accd[3] += wv * bf2f((unsigned short)(a8 >> 48));
        }
        float4 v;
        v.x = accd[0]; v.y = accd[1]; v.z = accd[2]; v.w = accd[3];
        *(float4*)(scratch + nset * 512 + dt * 4) = v;
    }
    lds_barrier();
    {
        float s = scratch[t] + scratch[512 + t] + scratch[1024 + t] + scratch[1536 + t];
        ctxp[(size_t)tile * 512 + t] = s;
    }
}

// ---- per-batch: global softmax (64 partials) + alpha + ctx merge ----
__global__ void combine_kernel(const float* __restrict__ scores,
                               const float* __restrict__ stats,
                               const float* __restrict__ ctxp,
                               float* __restrict__ out_ctx,
                               float* __restrict__ out_alpha) {
    __shared__ float scales[64];
    __shared__ float MZ[2];
    const int b = blockIdx.x, t = threadIdx.x;
    if (t < 64) {
        float mk = stats[(b * 64 + t) * 2];
        float lk = stats[(b * 64 + t) * 2 + 1];
        float M = mk;
#pragma unroll
        for (int off = 1; off < 64; off <<= 1) M = fmaxf(M, __shfl_xor(M, off, 64));
        float e = __expf(mk - M);
        float z = lk * e;
#pragma unroll
        for (int off = 1; off < 64; off <<= 1) z += __shfl_xor(z, off, 64);
        scales[t] = e / z;
        if (t == 0) { MZ[0] = M; MZ[1] = z; }
    }
    __syncthreads();
    const float M = MZ[0], invZ = 1.0f / MZ[1];
    const float* sb = scores + b * 4096;
    float* abp = out_alpha + b * 4096;
#pragma unroll
    for (int i = 0; i < 16; ++i) {
        int n = t + 256 * i;
        abp[n] = __expf(sb[n] - M) * invZ;
    }
    // 8-wide unrolled merge: 8 independent loads in flight
    const int d0 = t * 2;
    const float* cb = ctxp + (size_t)b * 64 * 512;
    float accx = 0.f, accy = 0.f;
    for (int k0 = 0; k0 < 64; k0 += 8) {
        float2 v[8]; float s[8];
#pragma unroll
        for (int u = 0; u < 8; ++u) {
            s[u] = scales[k0 + u];
            v[u] = *(const float2*)(cb + (size_t)(k0 + u) * 512 + d0);
        }
#pragma unroll
        for (int u = 0; u < 8; ++u) { accx += s[u] * v[u].x; accy += s[u] * v[u].y; }
    }
    float2 o; o.x = accx; o.y = accy;
    *(float2*)(out_ctx + b * 512 + d0) = o;
}

extern "C" void kernel_launch(void* const* d_in, const int* in_sizes, int n_in,
                              void* d_out, int out_size, void* d_ws, size_t ws_size,
                              hipStream_t stream) {
    (void)in_sizes; (void)n_in; (void)out_size;
    const float* feats  = (const float*)d_in[0];
    const float* hidden = (const float*)d_in[1];
    const float* Wf     = (const float*)d_in[2];
    const float* bfv    = (const float*)d_in[3];
    const float* Wh     = (const float*)d_in[4];
    const float* bh     = (const float*)d_in[5];
    const float* Ws     = (const float*)d_in[6];
    // d_in[7] (bs) irrelevant: softmax is shift-invariant and scores are not output.

    char* ws = (char*)d_ws;
    unsigned short* WfT = (unsigned short*)(ws + WFT_OFF);
    float* hb     = (float*)(ws + HB_OFF);
    float* scores = (float*)(ws + SC_OFF);
    float* stats  = (float*)(ws + ST_OFF);
    float* ctxp   = (float*)(ws + CP_OFF);
    char*  img    = ws + IMG_OFF;

    float* out_ctx   = (float*)d_out;
    float* out_alpha = out_ctx + 32 * 512;

    hipFuncSetAttribute((const void*)main_img,
                        hipFuncAttributeMaxDynamicSharedMemorySize, SMEM_IMG);
    hipFuncSetAttribute((const void*)main_fb,
                        hipFuncAttributeMaxDynamicSharedMemorySize, SMEM_FB);

    hipLaunchKernelGGL(wft_kernel, dim3(32), dim3(256), 0, stream, Wf, WfT);
    hipLaunchKernelGGL(hb_kernel, dim3(32), dim3(256), 0, stream, hidden, Wh, bh, bfv, hb);

    if (ws_size >= (size_t)WS_NEED) {
        hipLaunchKernelGGL(prep_kernel, dim3(2048), dim3(256), 0, stream, feats, img);
        hipLaunchKernelGGL(main_img, dim3(256), dim3(512), SMEM_IMG, stream,
                           img, WfT, hb, Ws, scores, stats, ctxp);
    } else {
        hipLaunchKernelGGL(main_fb, dim3(2048), dim3(512), SMEM_FB, stream,
                           feats, WfT, hb, Ws, scores, stats, ctxp);
    }
    hipLaunchKernelGGL(combine_kernel, dim3(32), dim3(256), 0, stream,
                       scores, stats, ctxp, out_ctx, out_alpha);
}

// Round 6
// 184.690 us; speedup vs baseline: 1.5255x; 1.2319x over previous
//
#include <hip/hip_runtime.h>
#include <hip/hip_bf16.h>

typedef __attribute__((ext_vector_type(8))) short short8;
typedef __attribute__((ext_vector_type(4))) float f32x4;

// ws layout (bytes)
#define WFT_OFF 0          // bf16[256*512]          = 262144 B
#define HB_OFF  262144     // f32[32*256]            =  32768 B
#define SC_OFF  294912     // f32[131072] scores     = 524288 B
#define ST_OFF  819200     // f32[2048*2] m,l        =  16384 B
#define CP_OFF  835584     // f32[2048*512] ctx part = 4194304 B (total ~5 MB)

// scores_kernel LDS: Ab [64][1024B] bf16 swizzled @0, wpart[8][64] @65536
#define SMEM_S 67584

__device__ __forceinline__ float bf2f(unsigned short h) {
    unsigned u = ((unsigned)h) << 16;
    return __builtin_bit_cast(float, u);
}
__device__ __forceinline__ unsigned pack_bf16(float a, float b) {
    unsigned short sa = __builtin_bit_cast(unsigned short, __float2bfloat16(a));
    unsigned short sb = __builtin_bit_cast(unsigned short, __float2bfloat16(b));
    return (unsigned)sa | ((unsigned)sb << 16);
}
__device__ __forceinline__ float fast_tanh(float x) {
    float e2 = __expf(2.0f * x);
    return 1.0f - 2.0f / (e2 + 1.0f);
}
__device__ __forceinline__ void lds_barrier() {
    asm volatile("s_waitcnt lgkmcnt(0)" ::: "memory");
    __builtin_amdgcn_s_barrier();
}

// ---- Wf (512x256 f32) -> WfT (256x512 bf16), tiled transpose ----
__global__ void wft_kernel(const float* __restrict__ Wf, unsigned short* __restrict__ WfT) {
    __shared__ unsigned short tl[64 * 80];
    const int t = threadIdx.x;
    const int tk = blockIdx.x >> 2, ta = blockIdx.x & 3;
    const int d0 = tk * 64, a0 = ta * 64;
#pragma unroll
    for (int i = 0; i < 16; ++i) {
        int flat = t + 256 * i;
        int dl = flat >> 6, al = flat & 63;
        tl[al * 80 + dl] = __builtin_bit_cast(unsigned short,
                               __float2bfloat16(Wf[(d0 + dl) * 256 + a0 + al]));
    }
    __syncthreads();
#pragma unroll
    for (int i = 0; i < 2; ++i) {
        int u = t + 256 * i;
        int al = u >> 3, q = u & 7;
        *(uint4*)(&WfT[(size_t)(a0 + al) * 512 + d0 + q * 8]) =
            *(const uint4*)(&tl[al * 80 + q * 8]);
    }
}

// ---- hb[b][a] = hidden[b]·Wh[:,a] + bh[a] + bf[a] ----
__global__ void hb_kernel(const float* __restrict__ hidden, const float* __restrict__ Wh,
                          const float* __restrict__ bh, const float* __restrict__ bfv,
                          float* __restrict__ hb) {
    const int b = blockIdx.x, a = threadIdx.x;
    float acc = bh[a] + bfv[a];
    const float* hrow = hidden + b * 512;
#pragma unroll 8
    for (int d = 0; d < 512; ++d)
        acc += hrow[d] * Wh[d * 256 + a];
    hb[b * 256 + a] = acc;
}

// ---- S: scores GEMM + tanh·Ws + per-tile softmax stats (NO ctx phase) ----
// R2-proven structure, ctx/scratch deleted: 2048 tiles x 64 rows, 512 thr,
// 66 KB LDS -> 2 blocks/CU. Measures the GEMM core in isolation.
__launch_bounds__(512, 4)
__global__ void scores_kernel(const float* __restrict__ feats,
                              const unsigned short* __restrict__ WfT,
                              const float* __restrict__ hbg,
                              const float* __restrict__ Ws,
                              float* __restrict__ scores,
                              float* __restrict__ stats) {
    extern __shared__ char smem[];
    char* Ab     = smem;                        // [64][1024 B] bf16, XOR-swizzled
    float* wpart = (float*)(smem + 65536);      // [8][64]

    const int t = threadIdx.x;
    const int tile = blockIdx.x;
    const int b = tile >> 6;
    const int row0 = tile * 64;
    const int lane = t & 63, w = t >> 6;        // 8 waves; wave w owns cols w*32..+31
    const int lr = lane & 15, lg = lane >> 4;
    const int sw = (lr & 7) << 4;

    // stage A tile: feats f32 -> bf16 LDS
    {
        const int ar = t >> 3;
        const int c8 = t & 7;
        const float4* fr = (const float4*)(feats + (size_t)(row0 + ar) * 512);
        char* arow = Ab + ar * 1024;
        const int rsw = (ar & 7) << 4;
#pragma unroll
        for (int i = 0; i < 16; ++i) {
            int f4 = c8 + i * 8;
            float4 v = fr[f4];
            uint2 u;
            u.x = pack_bf16(v.x, v.y);
            u.y = pack_bf16(v.z, v.w);
            *(uint2*)(arow + ((f4 * 8) ^ rsw)) = u;
        }
    }

    float hbv[2], wsv[2];
#pragma unroll
    for (int j = 0; j < 2; ++j) {
        int col = w * 32 + j * 16 + lr;
        hbv[j] = hbg[b * 256 + col];
        wsv[j] = Ws[col];
    }

    lds_barrier();

    // GEMM 64x256x512: wave w -> 64 rows x 32 cols, depth-2 B prefetch from L2
    const unsigned short* bp0 = WfT + (size_t)(w * 32 + lr) * 512 + lg * 8;
    const unsigned short* bp1 = WfT + (size_t)(w * 32 + 16 + lr) * 512 + lg * 8;
    uint4 bq[2][2];
    bq[0][0] = *(const uint4*)(bp0);
    bq[0][1] = *(const uint4*)(bp1);
    bq[1][0] = *(const uint4*)(bp0 + 32);
    bq[1][1] = *(const uint4*)(bp1 + 32);

    f32x4 acc[4][2] = {};
#pragma unroll
    for (int ks = 0; ks < 16; ++ks) {
        const int p = ks & 1;
        short8 af[4];
#pragma unroll
        for (int i = 0; i < 4; ++i) {
            int row = i * 16 + lr;
            af[i] = *(const short8*)(Ab + row * 1024 + ((ks * 64 + lg * 16) ^ sw));
        }
        short8 b0 = __builtin_bit_cast(short8, bq[p][0]);
        short8 b1 = __builtin_bit_cast(short8, bq[p][1]);
        if (ks < 14) {
            bq[p][0] = *(const uint4*)(bp0 + (ks + 2) * 32);
            bq[p][1] = *(const uint4*)(bp1 + (ks + 2) * 32);
        }
#pragma unroll
        for (int i = 0; i < 4; ++i) {
            acc[i][0] = __builtin_amdgcn_mfma_f32_16x16x32_bf16(af[i], b0, acc[i][0], 0, 0, 0);
            acc[i][1] = __builtin_amdgcn_mfma_f32_16x16x32_bf16(af[i], b1, acc[i][1], 0, 0, 0);
        }
    }

    // epilogue: scores = sum_a tanh(C + hb[a]) * Ws[a]
#pragma unroll
    for (int i = 0; i < 4; ++i) {
#pragma unroll
        for (int r = 0; r < 4; ++r) {
            float p = fast_tanh(acc[i][0][r] + hbv[0]) * wsv[0]
                    + fast_tanh(acc[i][1][r] + hbv[1]) * wsv[1];
#pragma unroll
            for (int off = 1; off < 16; off <<= 1) p += __shfl_xor(p, off, 64);
            if (lr == 0) wpart[w * 64 + i * 16 + lg * 4 + r] = p;
        }
    }
    lds_barrier();

    // per-tile softmax stats (wave 0)
    if (t < 64) {
        float s = 0.f;
#pragma unroll
        for (int k = 0; k < 8; ++k) s += wpart[k * 64 + t];
        scores[row0 + t] = s;
        float m = s;
#pragma unroll
        for (int off = 1; off < 64; off <<= 1) m = fmaxf(m, __shfl_xor(m, off, 64));
        float e = __expf(s - m);
        float l = e;
#pragma unroll
        for (int off = 1; off < 64; off <<= 1) l += __shfl_xor(l, off, 64);
        if (t == 0) { stats[tile * 2] = m; stats[tile * 2 + 1] = l; }
    }
}

// ---- C: ctx partials — pure feats stream (L3-hot from S), fill-kernel style ----
// 2048 blocks x 256 thr, 256 B LDS -> 8 blocks/CU, 32 waves/CU, no MFMA,
// 8-deep independent float2 loads. This kernel's hbm_gbps is the diagnostic.
__launch_bounds__(256, 8)
__global__ void ctx_kernel(const float* __restrict__ feats,
                           const float* __restrict__ scores,
                           const float* __restrict__ stats,
                           float* __restrict__ ctxp) {
    __shared__ float wbuf[64];
    const int tile = blockIdx.x;
    const int row0 = tile * 64;
    const int t = threadIdx.x;

    if (t < 64) wbuf[t] = __expf(scores[row0 + t] - stats[tile * 2]);
    __syncthreads();

    const float* fb = feats + (size_t)row0 * 512 + t * 2;
    float accx = 0.f, accy = 0.f;
    for (int n0 = 0; n0 < 64; n0 += 8) {
        float2 v[8]; float sc[8];
#pragma unroll
        for (int u = 0; u < 8; ++u) {
            sc[u] = wbuf[n0 + u];
            v[u]  = *(const float2*)(fb + (size_t)(n0 + u) * 512);
        }
#pragma unroll
        for (int u = 0; u < 8; ++u) { accx += sc[u] * v[u].x; accy += sc[u] * v[u].y; }
    }
    float2 o; o.x = accx; o.y = accy;
    *(float2*)(ctxp + (size_t)tile * 512 + t * 2) = o;
}

// ---- per-batch: global softmax (64 partials) + alpha + ctx merge ----
__global__ void combine_kernel(const float* __restrict__ scores,
                               const float* __restrict__ stats,
                               const float* __restrict__ ctxp,
                               float* __restrict__ out_ctx,
                               float* __restrict__ out_alpha) {
    __shared__ float scales[64];
    __shared__ float MZ[2];
    const int b = blockIdx.x, t = threadIdx.x;
    if (t < 64) {
        float mk = stats[(b * 64 + t) * 2];
        float lk = stats[(b * 64 + t) * 2 + 1];
        float M = mk;
#pragma unroll
        for (int off = 1; off < 64; off <<= 1) M = fmaxf(M, __shfl_xor(M, off, 64));
        float e = __expf(mk - M);
        float z = lk * e;
#pragma unroll
        for (int off = 1; off < 64; off <<= 1) z += __shfl_xor(z, off, 64);
        scales[t] = e / z;
        if (t == 0) { MZ[0] = M; MZ[1] = z; }
    }
    __syncthreads();
    const float M = MZ[0], invZ = 1.0f / MZ[1];
    const float* sb = scores + b * 4096;
    float* abp = out_alpha + b * 4096;
#pragma unroll
    for (int i = 0; i < 16; ++i) {
        int n = t + 256 * i;
        abp[n] = __expf(sb[n] - M) * invZ;
    }
    // 8-wide unrolled merge: 8 independent loads in flight
    const int d0 = t * 2;
    const float* cb = ctxp + (size_t)b * 64 * 512;
    float accx = 0.f, accy = 0.f;
    for (int k0 = 0; k0 < 64; k0 += 8) {
        float2 v[8]; float s[8];
#pragma unroll
        for (int u = 0; u < 8; ++u) {
            s[u] = scales[k0 + u];
            v[u] = *(const float2*)(cb + (size_t)(k0 + u) * 512 + d0);
        }
#pragma unroll
        for (int u = 0; u < 8; ++u) { accx += s[u] * v[u].x; accy += s[u] * v[u].y; }
    }
    float2 o; o.x = accx; o.y = accy;
    *(float2*)(out_ctx + b * 512 + d0) = o;
}

extern "C" void kernel_launch(void* const* d_in, const int* in_sizes, int n_in,
                              void* d_out, int out_size, void* d_ws, size_t ws_size,
                              hipStream_t stream) {
    (void)in_sizes; (void)n_in; (void)out_size; (void)ws_size;
    const float* feats  = (const float*)d_in[0];
    const float* hidden = (const float*)d_in[1];
    const float* Wf     = (const float*)d_in[2];
    const float* bfv    = (const float*)d_in[3];
    const float* Wh     = (const float*)d_in[4];
    const float* bh     = (const float*)d_in[5];
    const float* Ws     = (const float*)d_in[6];
    // d_in[7] (bs) irrelevant: softmax is shift-invariant and scores are not output.

    char* ws = (char*)d_ws;
    unsigned short* WfT = (unsigned short*)(ws + WFT_OFF);
    float* hb     = (float*)(ws + HB_OFF);
    float* scores = (float*)(ws + SC_OFF);
    float* stats  = (float*)(ws + ST_OFF);
    float* ctxp   = (float*)(ws + CP_OFF);

    float* out_ctx   = (float*)d_out;
    float* out_alpha = out_ctx + 32 * 512;

    hipFuncSetAttribute((const void*)scores_kernel,
                        hipFuncAttributeMaxDynamicSharedMemorySize, SMEM_S);

    hipLaunchKernelGGL(wft_kernel, dim3(32), dim3(256), 0, stream, Wf, WfT);
    hipLaunchKernelGGL(hb_kernel, dim3(32), dim3(256), 0, stream, hidden, Wh, bh, bfv, hb);
    hipLaunchKernelGGL(scores_kernel, dim3(2048), dim3(512), SMEM_S, stream,
                       feats, WfT, hb, Ws, scores, stats);
    hipLaunchKernelGGL(ctx_kernel, dim3(2048), dim3(256), 0, stream,
                       feats, scores, stats, ctxp);
    hipLaunchKernelGGL(combine_kernel, dim3(32), dim3(256), 0, stream,
                       scores, stats, ctxp, out_ctx, out_alpha);
}